// Round 9
// baseline (3735.691 us; speedup 1.0000x reference)
//
#include <hip/hip_runtime.h>

#define B_ 128
#define T_ 100
#define D_ 256
#define H_ 512
#define L_ 40000
#define S_ 10

__device__ __forceinline__ float sigm_(float x){ return 1.f/(1.f + __expf(-x)); }
__device__ __forceinline__ float tanh_(float x){ return 1.f - 2.f/(__expf(2.f*x) + 1.f); }

// ---------------- zero h0 (parity-0 buffer) ----------------
__global__ void k_zero(float* __restrict__ h0){
  h0[blockIdx.x*256 + threadIdx.x] = 0.f;       // 256 blocks -> B*H floats
}

// ---------------- slot projections: Es/Eq = embed @ W_o.T (10 x 512) ----------------
__global__ void k_prep(const float* __restrict__ embed_s, const float* __restrict__ embed_q,
                       const float* __restrict__ w_s, const float* __restrict__ w_q,
                       float* __restrict__ es_proj, float* __restrict__ eq_proj){
  int bid = blockIdx.x;                 // 40 blocks
  int table = bid/20, rem = bid%20, s = rem/2, half = rem%2;
  int jo = half*256 + threadIdx.x;
  const float* emb = (table ? embed_q : embed_s) + s*D_;
  const float* w   = (table ? w_q : w_s) + (size_t)(2*H_ + jo)*D_;   // o-gate rows
  float acc = 0.f;
  #pragma unroll 4
  for (int k=0;k<D_;++k) acc = fmaf(emb[k], w[k], acc);
  (table ? eq_proj : es_proj)[s*H_ + jo] = acc;
}

// ---------------- phase 1: P[t][b][j], j<512 = g-gate preact, j>=512 = o-gate preact ----------------
__global__ __launch_bounds__(256) void k_phase1(
  const int* __restrict__ batch_l, const float* __restrict__ embed_l,
  const float* __restrict__ w_ih, const float* __restrict__ b_ih, const float* __restrict__ b_hh,
  const float* __restrict__ t_ld, const float* __restrict__ t_hd,
  const int* __restrict__ t_l, const int* __restrict__ t_h,
  const float* __restrict__ d_ld, const float* __restrict__ d_hd,
  const int* __restrict__ d_l, const int* __restrict__ d_h,
  const float* __restrict__ es_proj, const float* __restrict__ eq_proj,
  float* __restrict__ P)
{
  __shared__ float As[8][72];
  __shared__ float Bs[8][72];
  __shared__ int ridx[64];
  int mt = blockIdx.x, jt = blockIdx.y;       // 200 x 16
  int t = mt >> 1, b0 = (mt & 1)*64;
  int tid = threadIdx.x;
  if (tid < 64) ridx[tid] = batch_l[(b0+tid)*T_ + t];
  __syncthreads();
  int ty = tid >> 4, tx = tid & 15;
  int r_s = tid >> 2;
  int kk_s = (tid & 3)*2;
  const float* arow = embed_l + (size_t)ridx[r_s]*D_ + kk_s;
  const float* brow = w_ih + (size_t)(2*H_ + jt*64 + r_s)*D_ + kk_s;
  float acc[4][4] = {};
  for (int kc = 0; kc < 32; ++kc) {
    int k0 = kc*8;
    float2 av = *(const float2*)(arow + k0);
    float2 bv = *(const float2*)(brow + k0);
    __syncthreads();
    As[kk_s][r_s] = av.x; As[kk_s+1][r_s] = av.y;
    Bs[kk_s][r_s] = bv.x; Bs[kk_s+1][r_s] = bv.y;
    __syncthreads();
    #pragma unroll
    for (int kk=0;kk<8;++kk){
      float4 a4 = *(const float4*)&As[kk][ty*4];
      float4 b4 = *(const float4*)&Bs[kk][tx*4];
      float avv[4] = {a4.x,a4.y,a4.z,a4.w};
      float bvv[4] = {b4.x,b4.y,b4.z,b4.w};
      #pragma unroll
      for (int i=0;i<4;++i)
        #pragma unroll
        for (int j=0;j<4;++j) acc[i][j] = fmaf(avv[i], bvv[j], acc[i][j]);
    }
  }
  int j0 = jt*64 + tx*4;
  float bias[4];
  #pragma unroll
  for (int j=0;j<4;++j) bias[j] = b_ih[2*H_ + j0 + j] + b_hh[2*H_ + j0 + j];
  #pragma unroll
  for (int i=0;i<4;++i){
    int b = b0 + ty*4 + i;
    size_t m = (size_t)t*B_ + b;
    float add[4] = {0.f,0.f,0.f,0.f};
    if (jt >= 8) {
      int bt = b*T_ + t;
      float dld = d_ld[bt], dhd = d_hd[bt];
      float tld = t_ld[bt], thd = t_hd[bt];
      int dl = d_l[bt], dh = d_h[bt], tl = t_l[bt], th = t_h[bt];
      int jo = j0 - 512;
      #pragma unroll
      for (int j=0;j<4;++j)
        add[j] = dhd*es_proj[dl*H_+jo+j] + dld*es_proj[dh*H_+jo+j]
               + thd*eq_proj[tl*H_+jo+j] + tld*eq_proj[th*H_+jo+j];
    }
    float4 o4;
    o4.x = acc[i][0] + bias[0] + add[0];
    o4.y = acc[i][1] + bias[1] + add[1];
    o4.z = acc[i][2] + bias[2] + add[2];
    o4.w = acc[i][3] + bias[3] + add[3];
    *(float4*)&P[m*1024 + j0] = o4;
  }
}

// ---------------- one recurrence step: h_next = sigm(o)*tanh(tanh(g)) ----------------
// Launched once per t (100 graph nodes). NO atomics, NO custom sync: kernel boundaries
// provide device-wide coherence (end-of-kernel release / start-of-kernel acquire).
// Grid 256 WGs x 512 thr = 16 bg (8 batches) x 16 js (32 j). Whh g/o rows in registers
// (w[4][16], 64 VGPR); h staged via LDS float4; butterfly reduce over 32-lane k groups.
// Compute core identical to the r5-verified skeleton.
__global__ __launch_bounds__(512,1) void k_step(
  const float* __restrict__ w_hh, const float* __restrict__ Pt,
  const float* __restrict__ h_prev, float* __restrict__ h_next)
{
  __shared__ float4 hta[512];                     // h[k][b0..b3]
  __shared__ float4 htb[512];                     // h[k][b4..b7]
  int bid = blockIdx.x;
  int bg = bid & 15, js = bid >> 4;
  int tid = threadIdx.x;
  int rq = tid >> 5;                              // 0..15 -> j-pair
  int kq = tid & 31;                              // 0..31 -> k split
  int j0 = js*32 + rq*2;
  const int gb0 = bg*8;
  const float* Wg = w_hh + (size_t)2*H_*H_;       // g rows [0,512)
  const float* Wo = w_hh + (size_t)3*H_*H_;       // o rows [0,512)

  // ---- h loads first (coalesced 256B per b), then P, then weights (latency overlap)
  const float* hsrc = h_prev + (size_t)gb0*H_ + tid;
  float hv[8];
  #pragma unroll
  for (int b=0;b<8;++b) hv[b] = hsrc[(size_t)b*H_];

  float2 pg = {0.f,0.f}, po = {0.f,0.f};
  if (kq < 8){
    size_t prow = (size_t)(gb0 + kq)*1024;
    pg = *(const float2*)&Pt[prow + j0];
    po = *(const float2*)&Pt[prow + 512 + j0];
  }

  // ---- weights -> registers: w[0..1]=g(j0,j0+1), w[2..3]=o(j0,j0+1); k = kk*32+kq
  float w[4][16];
  #pragma unroll
  for (int jj=0;jj<2;++jj){
    const float* sg = Wg + (size_t)(j0+jj)*H_ + kq;
    const float* so = Wo + (size_t)(j0+jj)*H_ + kq;
    #pragma unroll
    for (int kk=0;kk<16;++kk){ w[jj][kk] = sg[kk*32]; w[2+jj][kk] = so[kk*32]; }
  }

  hta[tid] = make_float4(hv[0],hv[1],hv[2],hv[3]);
  htb[tid] = make_float4(hv[4],hv[5],hv[6],hv[7]);
  __syncthreads();

  // ---- compute: acc[r][b] = sum over own k-slice of w[r][k]*h[k][b]
  float acc[4][8] = {};
  #pragma unroll
  for (int kk=0; kk<16; ++kk){
    float4 a  = hta[kk*32 + kq];
    float4 b4 = htb[kk*32 + kq];
    float hvv[8] = {a.x,a.y,a.z,a.w,b4.x,b4.y,b4.z,b4.w};
    #pragma unroll
    for (int r=0;r<4;++r)
      #pragma unroll
      for (int i=0;i<8;++i) acc[r][i] = fmaf(w[r][kk], hvv[i], acc[r][i]);
  }
  // ---- butterfly reduce over the 32-lane k groups (xor<=16 stays within half-wave)
  #pragma unroll
  for (int r=0;r<4;++r)
    #pragma unroll
    for (int i=0;i<8;++i){
      float s = acc[r][i];
      s += __shfl_xor(s, 1, 64);
      s += __shfl_xor(s, 2, 64);
      s += __shfl_xor(s, 4, 64);
      s += __shfl_xor(s, 8, 64);
      s += __shfl_xor(s, 16, 64);
      acc[r][i] = s;
    }
  // ---- epilogue: lane kq=b (b<8) stores h(j0),h(j0+1) for batch b
  if (kq < 8){
    int b = kq;
    float gg0 = acc[0][b] + pg.x, gg1 = acc[1][b] + pg.y;
    float oo0 = acc[2][b] + po.x, oo1 = acc[3][b] + po.y;
    float2 h2;
    h2.x = sigm_(oo0)*tanh_(tanh_(gg0));
    h2.y = sigm_(oo1)*tanh_(tanh_(gg1));
    *(float2*)&h_next[(size_t)(gb0 + b)*H_ + j0] = h2;
  }
}

// ---------------- classifier: out = hT @ w_out.T + b_out ----------------
__global__ __launch_bounds__(256) void k_cls(
  const float* __restrict__ hT, const float* __restrict__ w_out,
  const float* __restrict__ b_out, float* __restrict__ out)
{
  __shared__ float wt[32*68];     // [k][l] k-major
  __shared__ float htl[32*132];   // [k][b]
  int l0 = blockIdx.x * 64;       // 625 blocks
  int tid = threadIdx.x;
  int lq = tid >> 4, bq = tid & 15;
  float acc[4][8] = {};
  for (int kc=0; kc<16; ++kc){
    int k0 = kc*32;
    __syncthreads();
    for (int it=0; it<8; ++it){
      int e = it*256 + tid; int k = e & 31, l = e >> 5;
      wt[k*68 + l] = w_out[(size_t)(l0+l)*H_ + k0 + k];
    }
    for (int it=0; it<16; ++it){
      int e = it*256 + tid; int k = e & 31, b = e >> 5;
      htl[k*132 + b] = hT[(size_t)b*H_ + k0 + k];
    }
    __syncthreads();
    #pragma unroll 4
    for (int k=0;k<32;++k){
      float4 w4 = *(const float4*)&wt[k*68 + lq*4];
      float4 h0 = *(const float4*)&htl[k*132 + bq*8];
      float4 h1 = *(const float4*)&htl[k*132 + bq*8 + 4];
      float wv[4] = {w4.x,w4.y,w4.z,w4.w};
      float hv[8] = {h0.x,h0.y,h0.z,h0.w,h1.x,h1.y,h1.z,h1.w};
      #pragma unroll
      for (int m=0;m<4;++m)
        #pragma unroll
        for (int i=0;i<8;++i) acc[m][i] = fmaf(wv[m], hv[i], acc[m][i]);
    }
  }
  int l = l0 + lq*4;
  float4 bo = *(const float4*)&b_out[l];
  #pragma unroll
  for (int i=0;i<8;++i){
    int b = bq*8 + i;
    float4 o4;
    o4.x = acc[0][i] + bo.x; o4.y = acc[1][i] + bo.y;
    o4.z = acc[2][i] + bo.z; o4.w = acc[3][i] + bo.w;
    *(float4*)&out[(size_t)b*L_ + l] = o4;
  }
}

extern "C" void kernel_launch(void* const* d_in, const int* in_sizes, int n_in,
                              void* d_out, int out_size, void* d_ws, size_t ws_size,
                              hipStream_t stream) {
  const int*   batch_l = (const int*)  d_in[0];
  const float* t_ld    = (const float*)d_in[1];
  const float* t_hd    = (const float*)d_in[2];
  const int*   t_l     = (const int*)  d_in[3];
  const int*   t_h     = (const int*)  d_in[4];
  const float* d_ld    = (const float*)d_in[5];
  const float* d_hd    = (const float*)d_in[6];
  const int*   d_l     = (const int*)  d_in[7];
  const int*   d_h     = (const int*)  d_in[8];
  const float* embed_l = (const float*)d_in[9];
  const float* embed_s = (const float*)d_in[10];
  const float* embed_q = (const float*)d_in[11];
  const float* w_ih    = (const float*)d_in[12];
  const float* w_hh    = (const float*)d_in[13];
  const float* w_s     = (const float*)d_in[14];
  const float* w_q     = (const float*)d_in[15];
  const float* b_ih    = (const float*)d_in[16];
  const float* b_hh    = (const float*)d_in[17];
  const float* w_out   = (const float*)d_in[18];
  const float* b_out   = (const float*)d_in[19];
  float* out = (float*)d_out;

  // workspace layout (float offsets)
  float* ws = (float*)d_ws;
  const size_t P_off  = 0;                          // 13107200 f
  const size_t h_off  = 13107200;                   // 131072 f (2*B*H double buffer)
  const size_t es_off = h_off + 131072;             // 5120 f
  const size_t eq_off = es_off + 5120;              // 5120 f
  const size_t need_bytes = (eq_off + 5120)*4 + 64;
  if (ws_size < need_bytes) return;

  float* P       = ws + P_off;
  float* h_buf   = ws + h_off;
  float* es_proj = ws + es_off;
  float* eq_proj = ws + eq_off;

  k_zero<<<256, 256, 0, stream>>>(h_buf);           // zero parity-0 buffer (h at t=0)
  k_prep<<<40, 256, 0, stream>>>(embed_s, embed_q, w_s, w_q, es_proj, eq_proj);
  k_phase1<<<dim3(200,16), 256, 0, stream>>>(batch_l, embed_l, w_ih, b_ih, b_hh,
      t_ld, t_hd, t_l, t_h, d_ld, d_hd, d_l, d_h, es_proj, eq_proj, P);
  for (int t = 0; t < T_; ++t){
    const float* hp = h_buf + (size_t)(t & 1)*(B_*H_);
    float*       hn = h_buf + (size_t)((t+1) & 1)*(B_*H_);
    k_step<<<256, 512, 0, stream>>>(w_hh, P + (size_t)t*B_*1024, hp, hn);
  }
  // T_=100 is even -> final h lands in parity-0 buffer
  k_cls<<<625, 256, 0, stream>>>(h_buf, w_out, b_out, out);
}

// Round 10
// 3634.886 us; speedup vs baseline: 1.0277x; 1.0277x over previous
//
#include <hip/hip_runtime.h>

#define B_ 128
#define T_ 100
#define D_ 256
#define H_ 512
#define L_ 40000
#define S_ 10

__device__ __forceinline__ float sigm_(float x){ return 1.f/(1.f + __expf(-x)); }
__device__ __forceinline__ float tanh_(float x){ return 1.f - 2.f/(__expf(2.f*x) + 1.f); }

union F2U64 { float2 f; unsigned long long u; };

// ---------------- zero h double-buffer + flags ----------------
__global__ void k_zero(float* __restrict__ h_buf, unsigned* __restrict__ flags){
  int idx = blockIdx.x*256 + threadIdx.x;
  if (blockIdx.x < 512) h_buf[idx] = 0.f;            // 2*B*H floats
  else flags[idx - 512*256] = 0u;                    // blocks 512..575 -> 16384 u32
}

// ---------------- slot projections: Es/Eq = embed @ W_o.T (10 x 512) ----------------
__global__ void k_prep(const float* __restrict__ embed_s, const float* __restrict__ embed_q,
                       const float* __restrict__ w_s, const float* __restrict__ w_q,
                       float* __restrict__ es_proj, float* __restrict__ eq_proj){
  int bid = blockIdx.x;                 // 40 blocks
  int table = bid/20, rem = bid%20, s = rem/2, half = rem%2;
  int jo = half*256 + threadIdx.x;
  const float* emb = (table ? embed_q : embed_s) + s*D_;
  const float* w   = (table ? w_q : w_s) + (size_t)(2*H_ + jo)*D_;   // o-gate rows
  float acc = 0.f;
  #pragma unroll 4
  for (int k=0;k<D_;++k) acc = fmaf(emb[k], w[k], acc);
  (table ? eq_proj : es_proj)[s*H_ + jo] = acc;
}

// ---------------- phase 1: P[t][b][j], j<512 = g-gate preact, j>=512 = o-gate preact ----------------
__global__ __launch_bounds__(256) void k_phase1(
  const int* __restrict__ batch_l, const float* __restrict__ embed_l,
  const float* __restrict__ w_ih, const float* __restrict__ b_ih, const float* __restrict__ b_hh,
  const float* __restrict__ t_ld, const float* __restrict__ t_hd,
  const int* __restrict__ t_l, const int* __restrict__ t_h,
  const float* __restrict__ d_ld, const float* __restrict__ d_hd,
  const int* __restrict__ d_l, const int* __restrict__ d_h,
  const float* __restrict__ es_proj, const float* __restrict__ eq_proj,
  float* __restrict__ P)
{
  __shared__ float As[8][72];
  __shared__ float Bs[8][72];
  __shared__ int ridx[64];
  int mt = blockIdx.x, jt = blockIdx.y;       // 200 x 16
  int t = mt >> 1, b0 = (mt & 1)*64;
  int tid = threadIdx.x;
  if (tid < 64) ridx[tid] = batch_l[(b0+tid)*T_ + t];
  __syncthreads();
  int ty = tid >> 4, tx = tid & 15;
  int r_s = tid >> 2;
  int kk_s = (tid & 3)*2;
  const float* arow = embed_l + (size_t)ridx[r_s]*D_ + kk_s;
  const float* brow = w_ih + (size_t)(2*H_ + jt*64 + r_s)*D_ + kk_s;
  float acc[4][4] = {};
  for (int kc = 0; kc < 32; ++kc) {
    int k0 = kc*8;
    float2 av = *(const float2*)(arow + k0);
    float2 bv = *(const float2*)(brow + k0);
    __syncthreads();
    As[kk_s][r_s] = av.x; As[kk_s+1][r_s] = av.y;
    Bs[kk_s][r_s] = bv.x; Bs[kk_s+1][r_s] = bv.y;
    __syncthreads();
    #pragma unroll
    for (int kk=0;kk<8;++kk){
      float4 a4 = *(const float4*)&As[kk][ty*4];
      float4 b4 = *(const float4*)&Bs[kk][tx*4];
      float avv[4] = {a4.x,a4.y,a4.z,a4.w};
      float bvv[4] = {b4.x,b4.y,b4.z,b4.w};
      #pragma unroll
      for (int i=0;i<4;++i)
        #pragma unroll
        for (int j=0;j<4;++j) acc[i][j] = fmaf(avv[i], bvv[j], acc[i][j]);
    }
  }
  int j0 = jt*64 + tx*4;
  float bias[4];
  #pragma unroll
  for (int j=0;j<4;++j) bias[j] = b_ih[2*H_ + j0 + j] + b_hh[2*H_ + j0 + j];
  #pragma unroll
  for (int i=0;i<4;++i){
    int b = b0 + ty*4 + i;
    size_t m = (size_t)t*B_ + b;
    float add[4] = {0.f,0.f,0.f,0.f};
    if (jt >= 8) {
      int bt = b*T_ + t;
      float dld = d_ld[bt], dhd = d_hd[bt];
      float tld = t_ld[bt], thd = t_hd[bt];
      int dl = d_l[bt], dh = d_h[bt], tl = t_l[bt], th = t_h[bt];
      int jo = j0 - 512;
      #pragma unroll
      for (int j=0;j<4;++j)
        add[j] = dhd*es_proj[dl*H_+jo+j] + dld*es_proj[dh*H_+jo+j]
               + thd*eq_proj[tl*H_+jo+j] + tld*eq_proj[th*H_+jo+j];
    }
    float4 o4;
    o4.x = acc[i][0] + bias[0] + add[0];
    o4.y = acc[i][1] + bias[1] + add[1];
    o4.z = acc[i][2] + bias[2] + add[2];
    o4.w = acc[i][3] + bias[3] + add[3];
    *(float4*)&P[m*1024 + j0] = o4;
  }
}

// ---------------- recurrence: persistent, 256 WGs x 512 thr = 16 bg x 16 js ----------------
// Round-10 = r3's PROVEN protocol shell + r7's PROVEN register-weight compute core.
//  - Whh g/o rows in registers (w[4][16], 64 regs/thread); h staged as float4 LDS tiles.
//  - Cross-WG h exchange via relaxed agent-scope atomics (LLC/HBM-direct, no fences).
//  - Per-WG progress flag on its OWN 256B-padded line (no shared-line RMW serialization);
//    polled by only 16 threads (poll traffic stays tiny — r7's lesson).
//  - flag[js]=s means "WG js stored all of h(s)" (set after __syncthreads' vmcnt(0) drain,
//    so data is globally visible before the flag). At step t, consumers poll all 16 bg
//    flags >= t. Overwrite safety: a producer stores h(t+2) (over h(t), same parity) only
//    after passing poll(>=t+1); flag[js]>=t+1 implies js finished READING h(t) (its reads
//    at step t precede its h(t+1) stores). So no producer clobbers unread data.
__global__ __launch_bounds__(512,1) void k_rec(
  const float* __restrict__ w_hh, const float* __restrict__ P,
  float* __restrict__ h_buf, unsigned* __restrict__ flags)
{
  __shared__ float4 hta[512];                     // h[k][b0..b3]
  __shared__ float4 htb[512];                     // h[k][b4..b7]
  int bid = blockIdx.x;
  int bg = bid & 15, js = bid >> 4;
  int tid = threadIdx.x;
  int rq = tid >> 5;                              // 0..15 -> j-pair
  int kq = tid & 31;                              // 0..31 -> k split
  int j0 = js*32 + rq*2;
  const int gb0 = bg*8;
  const float* Wg = w_hh + (size_t)2*H_*H_;       // g rows [0,512)
  const float* Wo = w_hh + (size_t)3*H_*H_;       // o rows [0,512)

  // ---- weights -> registers: w[0..1]=g(j0,j0+1), w[2..3]=o(j0,j0+1); k = kk*32+kq
  float w[4][16];
  #pragma unroll
  for (int jj=0;jj<2;++jj){
    const float* sg = Wg + (size_t)(j0+jj)*H_ + kq;
    const float* so = Wo + (size_t)(j0+jj)*H_ + kq;
    #pragma unroll
    for (int kk=0;kk<16;++kk){ w[jj][kk] = sg[kk*32]; w[2+jj][kk] = so[kk*32]; }
  }

  unsigned* bgflags = flags + bg*16*64;           // this bg's 16 flag lines (256B apart)

  // ---- P prefetch for t=0 (lane kq<8 owns batch b=kq)
  float2 pg = {0.f,0.f}, po = {0.f,0.f};
  if (kq < 8){
    size_t prow = (size_t)(gb0 + kq)*1024;
    pg = *(const float2*)&P[prow + j0];
    po = *(const float2*)&P[prow + 512 + j0];
  }

  for (int t=0; t<T_; ++t){
    int par = t & 1;
    if (t > 0){
      if (tid < 16){                              // 16 parallel pollers, one line each
        unsigned* f = bgflags + tid*64;
        int guard = 0;
        while (__hip_atomic_load(f, __ATOMIC_RELAXED, __HIP_MEMORY_SCOPE_AGENT) < (unsigned)t){
          __builtin_amdgcn_s_sleep(1);
          if (++guard > (1<<22)) break;           // safety bail (never in normal operation)
        }
      }
      __syncthreads();
    }
    // ---- stage h[8 batches][k=tid] -> LDS (relaxed LLC loads see peers' stores)
    const float* hsrc = h_buf + (size_t)par*(B_*H_) + (size_t)gb0*H_ + tid;
    float hv[8];
    #pragma unroll
    for (int b=0;b<8;++b)
      hv[b] = __uint_as_float(__hip_atomic_load((const unsigned*)(hsrc + (size_t)b*H_),
                                                __ATOMIC_RELAXED, __HIP_MEMORY_SCOPE_AGENT));
    hta[tid] = make_float4(hv[0],hv[1],hv[2],hv[3]);
    htb[tid] = make_float4(hv[4],hv[5],hv[6],hv[7]);
    __syncthreads();

    // ---- compute: acc[r][b] = sum over own k-slice of w[r][k]*h[k][b]
    float acc[4][8] = {};
    #pragma unroll
    for (int kk=0; kk<16; ++kk){
      float4 a  = hta[kk*32 + kq];
      float4 b4 = htb[kk*32 + kq];
      float hvv[8] = {a.x,a.y,a.z,a.w,b4.x,b4.y,b4.z,b4.w};
      #pragma unroll
      for (int r=0;r<4;++r)
        #pragma unroll
        for (int i=0;i<8;++i) acc[r][i] = fmaf(w[r][kk], hvv[i], acc[r][i]);
    }
    // ---- butterfly reduce over the 32-lane k groups (xor<=16 stays within half-wave)
    #pragma unroll
    for (int r=0;r<4;++r)
      #pragma unroll
      for (int i=0;i<8;++i){
        float s = acc[r][i];
        s += __shfl_xor(s, 1, 64);
        s += __shfl_xor(s, 2, 64);
        s += __shfl_xor(s, 4, 64);
        s += __shfl_xor(s, 8, 64);
        s += __shfl_xor(s, 16, 64);
        acc[r][i] = s;
      }
    // ---- epilogue: lane kq=b (b<8) stores h(j0),h(j0+1) for batch b as one u64 atomic
    if (kq < 8){
      int b = kq;
      float gg0 = acc[0][b] + pg.x, gg1 = acc[1][b] + pg.y;
      float oo0 = acc[2][b] + po.x, oo1 = acc[3][b] + po.y;
      F2U64 h2;
      h2.f.x = sigm_(oo0)*tanh_(tanh_(gg0));
      h2.f.y = sigm_(oo1)*tanh_(tanh_(gg1));
      __hip_atomic_store((unsigned long long*)
        (h_buf + (size_t)(1-par)*(B_*H_) + (size_t)(gb0 + b)*H_ + j0),
        h2.u, __ATOMIC_RELAXED, __HIP_MEMORY_SCOPE_AGENT);
    }
    __syncthreads();   // per-wave vmcnt(0): all h stores globally visible past here
    if (t+1 < T_){
      if (tid == 0)
        __hip_atomic_store(bgflags + js*64, (unsigned)(t+1),
                           __ATOMIC_RELAXED, __HIP_MEMORY_SCOPE_AGENT);
      if (kq < 8){   // prefetch next step's P; overlaps with peers' completion
        size_t prow = ((size_t)(t+1)*B_ + gb0 + kq)*1024;
        pg = *(const float2*)&P[prow + j0];
        po = *(const float2*)&P[prow + 512 + j0];
      }
    }
  }
}

// ---------------- classifier: out = hT @ w_out.T + b_out ----------------
__global__ __launch_bounds__(256) void k_cls(
  const float* __restrict__ hT, const float* __restrict__ w_out,
  const float* __restrict__ b_out, float* __restrict__ out)
{
  __shared__ float wt[32*68];     // [k][l] k-major
  __shared__ float htl[32*132];   // [k][b]
  int l0 = blockIdx.x * 64;       // 625 blocks
  int tid = threadIdx.x;
  int lq = tid >> 4, bq = tid & 15;
  float acc[4][8] = {};
  for (int kc=0; kc<16; ++kc){
    int k0 = kc*32;
    __syncthreads();
    for (int it=0; it<8; ++it){
      int e = it*256 + tid; int k = e & 31, l = e >> 5;
      wt[k*68 + l] = w_out[(size_t)(l0+l)*H_ + k0 + k];
    }
    for (int it=0; it<16; ++it){
      int e = it*256 + tid; int k = e & 31, b = e >> 5;
      htl[k*132 + b] = hT[(size_t)b*H_ + k0 + k];
    }
    __syncthreads();
    #pragma unroll 4
    for (int k=0;k<32;++k){
      float4 w4 = *(const float4*)&wt[k*68 + lq*4];
      float4 h0 = *(const float4*)&htl[k*132 + bq*8];
      float4 h1 = *(const float4*)&htl[k*132 + bq*8 + 4];
      float wv[4] = {w4.x,w4.y,w4.z,w4.w};
      float hv[8] = {h0.x,h0.y,h0.z,h0.w,h1.x,h1.y,h1.z,h1.w};
      #pragma unroll
      for (int m=0;m<4;++m)
        #pragma unroll
        for (int i=0;i<8;++i) acc[m][i] = fmaf(wv[m], hv[i], acc[m][i]);
    }
  }
  int l = l0 + lq*4;
  float4 bo = *(const float4*)&b_out[l];
  #pragma unroll
  for (int i=0;i<8;++i){
    int b = bq*8 + i;
    float4 o4;
    o4.x = acc[0][i] + bo.x; o4.y = acc[1][i] + bo.y;
    o4.z = acc[2][i] + bo.z; o4.w = acc[3][i] + bo.w;
    *(float4*)&out[(size_t)b*L_ + l] = o4;
  }
}

extern "C" void kernel_launch(void* const* d_in, const int* in_sizes, int n_in,
                              void* d_out, int out_size, void* d_ws, size_t ws_size,
                              hipStream_t stream) {
  const int*   batch_l = (const int*)  d_in[0];
  const float* t_ld    = (const float*)d_in[1];
  const float* t_hd    = (const float*)d_in[2];
  const int*   t_l     = (const int*)  d_in[3];
  const int*   t_h     = (const int*)  d_in[4];
  const float* d_ld    = (const float*)d_in[5];
  const float* d_hd    = (const float*)d_in[6];
  const int*   d_l     = (const int*)  d_in[7];
  const int*   d_h     = (const int*)  d_in[8];
  const float* embed_l = (const float*)d_in[9];
  const float* embed_s = (const float*)d_in[10];
  const float* embed_q = (const float*)d_in[11];
  const float* w_ih    = (const float*)d_in[12];
  const float* w_hh    = (const float*)d_in[13];
  const float* w_s     = (const float*)d_in[14];
  const float* w_q     = (const float*)d_in[15];
  const float* b_ih    = (const float*)d_in[16];
  const float* b_hh    = (const float*)d_in[17];
  const float* w_out   = (const float*)d_in[18];
  const float* b_out   = (const float*)d_in[19];
  float* out = (float*)d_out;

  // workspace layout (float offsets)
  float* ws = (float*)d_ws;
  const size_t P_off   = 0;                         // 13107200 f
  const size_t h_off   = 13107200;                  // 131072 f (2*B*H double buffer)
  const size_t es_off  = h_off + 131072;            // 5120 f
  const size_t eq_off  = es_off + 5120;             // 5120 f
  const size_t flg_off = eq_off + 5120;             // 16384 u32 (256 flags, 256B apart)
  const size_t need_bytes = (flg_off + 16384)*4 + 64;
  if (ws_size < need_bytes) return;

  float* P        = ws + P_off;
  float* h_buf    = ws + h_off;
  float* es_proj  = ws + es_off;
  float* eq_proj  = ws + eq_off;
  unsigned* flags = (unsigned*)(ws + flg_off);

  k_zero<<<576, 256, 0, stream>>>(h_buf, flags);
  k_prep<<<40, 256, 0, stream>>>(embed_s, embed_q, w_s, w_q, es_proj, eq_proj);
  k_phase1<<<dim3(200,16), 256, 0, stream>>>(batch_l, embed_l, w_ih, b_ih, b_hh,
      t_ld, t_hd, t_l, t_h, d_ld, d_hd, d_l, d_h, es_proj, eq_proj, P);
  k_rec<<<256, 512, 0, stream>>>(w_hh, P, h_buf, flags);
  k_cls<<<625, 256, 0, stream>>>(h_buf, w_out, b_out, out);
}

// Round 11
// 896.156 us; speedup vs baseline: 4.1686x; 4.0561x over previous
//
#include <hip/hip_runtime.h>

#define B_ 128
#define T_ 100
#define D_ 256
#define H_ 512
#define L_ 40000
#define S_ 10

__device__ __forceinline__ float sigm_(float x){ return 1.f/(1.f + __expf(-x)); }
__device__ __forceinline__ float tanh_(float x){ return 1.f - 2.f/(__expf(2.f*x) + 1.f); }

union F2U64 { float2 f; unsigned long long u; };

// ---------------- zero h double-buffer + flags ----------------
__global__ void k_zero(float* __restrict__ h_buf, unsigned* __restrict__ flags){
  int idx = blockIdx.x*256 + threadIdx.x;
  if (blockIdx.x < 512) h_buf[idx] = 0.f;            // 2*B*H floats
  else if (threadIdx.x < 256) flags[threadIdx.x] = 0u;  // 256 u32 (16 bg x 16 js)
}

// ---------------- slot projections: Es/Eq = embed @ W_o.T (10 x 512) ----------------
__global__ void k_prep(const float* __restrict__ embed_s, const float* __restrict__ embed_q,
                       const float* __restrict__ w_s, const float* __restrict__ w_q,
                       float* __restrict__ es_proj, float* __restrict__ eq_proj){
  int bid = blockIdx.x;                 // 40 blocks
  int table = bid/20, rem = bid%20, s = rem/2, half = rem%2;
  int jo = half*256 + threadIdx.x;
  const float* emb = (table ? embed_q : embed_s) + s*D_;
  const float* w   = (table ? w_q : w_s) + (size_t)(2*H_ + jo)*D_;   // o-gate rows
  float acc = 0.f;
  #pragma unroll 4
  for (int k=0;k<D_;++k) acc = fmaf(emb[k], w[k], acc);
  (table ? eq_proj : es_proj)[s*H_ + jo] = acc;
}

// ---------------- phase 1: P[t][b][j], j<512 = g-gate preact, j>=512 = o-gate preact ----------------
__global__ __launch_bounds__(256) void k_phase1(
  const int* __restrict__ batch_l, const float* __restrict__ embed_l,
  const float* __restrict__ w_ih, const float* __restrict__ b_ih, const float* __restrict__ b_hh,
  const float* __restrict__ t_ld, const float* __restrict__ t_hd,
  const int* __restrict__ t_l, const int* __restrict__ t_h,
  const float* __restrict__ d_ld, const float* __restrict__ d_hd,
  const int* __restrict__ d_l, const int* __restrict__ d_h,
  const float* __restrict__ es_proj, const float* __restrict__ eq_proj,
  float* __restrict__ P)
{
  __shared__ float As[8][72];
  __shared__ float Bs[8][72];
  __shared__ int ridx[64];
  int mt = blockIdx.x, jt = blockIdx.y;       // 200 x 16
  int t = mt >> 1, b0 = (mt & 1)*64;
  int tid = threadIdx.x;
  if (tid < 64) ridx[tid] = batch_l[(b0+tid)*T_ + t];
  __syncthreads();
  int ty = tid >> 4, tx = tid & 15;
  int r_s = tid >> 2;
  int kk_s = (tid & 3)*2;
  const float* arow = embed_l + (size_t)ridx[r_s]*D_ + kk_s;
  const float* brow = w_ih + (size_t)(2*H_ + jt*64 + r_s)*D_ + kk_s;
  float acc[4][4] = {};
  for (int kc = 0; kc < 32; ++kc) {
    int k0 = kc*8;
    float2 av = *(const float2*)(arow + k0);
    float2 bv = *(const float2*)(brow + k0);
    __syncthreads();
    As[kk_s][r_s] = av.x; As[kk_s+1][r_s] = av.y;
    Bs[kk_s][r_s] = bv.x; Bs[kk_s+1][r_s] = bv.y;
    __syncthreads();
    #pragma unroll
    for (int kk=0;kk<8;++kk){
      float4 a4 = *(const float4*)&As[kk][ty*4];
      float4 b4 = *(const float4*)&Bs[kk][tx*4];
      float avv[4] = {a4.x,a4.y,a4.z,a4.w};
      float bvv[4] = {b4.x,b4.y,b4.z,b4.w};
      #pragma unroll
      for (int i=0;i<4;++i)
        #pragma unroll
        for (int j=0;j<4;++j) acc[i][j] = fmaf(avv[i], bvv[j], acc[i][j]);
    }
  }
  int j0 = jt*64 + tx*4;
  float bias[4];
  #pragma unroll
  for (int j=0;j<4;++j) bias[j] = b_ih[2*H_ + j0 + j] + b_hh[2*H_ + j0 + j];
  #pragma unroll
  for (int i=0;i<4;++i){
    int b = b0 + ty*4 + i;
    size_t m = (size_t)t*B_ + b;
    float add[4] = {0.f,0.f,0.f,0.f};
    if (jt >= 8) {
      int bt = b*T_ + t;
      float dld = d_ld[bt], dhd = d_hd[bt];
      float tld = t_ld[bt], thd = t_hd[bt];
      int dl = d_l[bt], dh = d_h[bt], tl = t_l[bt], th = t_h[bt];
      int jo = j0 - 512;
      #pragma unroll
      for (int j=0;j<4;++j)
        add[j] = dhd*es_proj[dl*H_+jo+j] + dld*es_proj[dh*H_+jo+j]
               + thd*eq_proj[tl*H_+jo+j] + tld*eq_proj[th*H_+jo+j];
    }
    float4 o4;
    o4.x = acc[i][0] + bias[0] + add[0];
    o4.y = acc[i][1] + bias[1] + add[1];
    o4.z = acc[i][2] + bias[2] + add[2];
    o4.w = acc[i][3] + bias[3] + add[3];
    *(float4*)&P[m*1024 + j0] = o4;
  }
}

// ---------------- recurrence: persistent, 256 WGs x 256 thr = 16 bg x 16 js ----------------
// Round-11 = r3's proven shell (256 thr, LDS weights, u64 relaxed-atomic h exchange,
// VGPR ~60-70 regime where WRITE_SIZE stayed small) with two fixes:
//  (1) h in LDS as float4 arrays -> inner loop 4 LDS ops/kk (2xb64 w + 2xb128 h),
//      conflict-free (r3 had 10 ops/kk and 5.1M bank conflicts).
//  (2) sync via 16 flag STORES into ONE 64B line per bg (no RMW serialization),
//      polled by 16 parallel lanes = one coalesced line-read per iteration.
// flag[bg][js]=s means "WG js stored all of h(s)": set after __syncthreads (per-wave
// vmcnt(0) drains both its h loads and h stores). Overwrite safety: producer stores
// h(t+2) over h(t) (same parity) only after poll(>=t+1): flag[p]>=t+1 implies peer p
// finished READING h(t) (reads precede its h(t+1) stores + drain). Max skew 1 step.
__global__ __launch_bounds__(256,1) void k_rec(
  const float* __restrict__ w_hh, const float* __restrict__ P,
  float* __restrict__ h_buf, unsigned* __restrict__ flags)
{
  extern __shared__ float sm[];
  float* Wt = sm;                               // [512][66] k-major, r = 4rq+{g0,g1,o0,o1}
  float4* hta = (float4*)(sm + 512*66);         // [512]: h[k][b0..b3]
  float4* htb = hta + 512;                      // [512]: h[k][b4..b7]
  int bid = blockIdx.x;
  int bg = bid & 15, js = bid >> 4;
  int tid = threadIdx.x;
  const float* Wgo = w_hh + (size_t)2*H_*H_;    // rows [0,512)=g, [512,1024)=o
  for (int it=0; it<32; ++it){                  // stage 64x512 weights (r3-exact)
    int e4 = (it*256 + tid)*4;
    int k = e4 & 511, r = e4 >> 9;
    int jh_loc = 2*(r>>2) + (r&1);
    int part = (r>>1)&1;
    int grow = part*H_ + js*32 + jh_loc;
    float4 v = *(const float4*)(Wgo + (size_t)grow*H_ + k);
    Wt[(k+0)*66 + r] = v.x; Wt[(k+1)*66 + r] = v.y;
    Wt[(k+2)*66 + r] = v.z; Wt[(k+3)*66 + r] = v.w;
  }
  int rq = tid >> 4, kq = tid & 15;
  int j0 = js*32 + 2*rq;
  const int gb0 = bg*8;
  unsigned* bgflags = flags + bg*16;            // 16 u32 in one 64B line

  // ---- P prefetch for t=0 (lane kq<8 owns batch b=kq)
  float2 pg = {0.f,0.f}, po = {0.f,0.f};
  if (kq < 8){
    size_t prow = (size_t)(gb0 + kq)*1024;
    pg = *(const float2*)&P[prow + j0];
    po = *(const float2*)&P[prow + 512 + j0];
  }
  __syncthreads();                              // weights staged

  for (int t=0; t<T_; ++t){
    int par = t & 1;
    if (t > 0){
      if (tid < 16){                            // one coalesced 64B line read per poll
        unsigned* f = bgflags + tid;
        int guard = 0;
        while (__hip_atomic_load(f, __ATOMIC_RELAXED, __HIP_MEMORY_SCOPE_AGENT) < (unsigned)t){
          __builtin_amdgcn_s_sleep(4);
          if (++guard > (1<<22)) break;         // safety bail (never in normal operation)
        }
      }
      __syncthreads();
    }
    // ---- stage h: thread tid loads u64 pair (k=2tid, 2tid+1) for b=0..7
    const unsigned long long* hsrc =
      (const unsigned long long*)(h_buf + (size_t)par*(B_*H_) + (size_t)gb0*H_) + tid;
    F2U64 v[8];
    #pragma unroll
    for (int b=0;b<8;++b)
      v[b].u = __hip_atomic_load(&hsrc[b*(H_/2)], __ATOMIC_RELAXED, __HIP_MEMORY_SCOPE_AGENT);
    hta[2*tid]   = make_float4(v[0].f.x, v[1].f.x, v[2].f.x, v[3].f.x);
    hta[2*tid+1] = make_float4(v[0].f.y, v[1].f.y, v[2].f.y, v[3].f.y);
    htb[2*tid]   = make_float4(v[4].f.x, v[5].f.x, v[6].f.x, v[7].f.x);
    htb[2*tid+1] = make_float4(v[4].f.y, v[5].f.y, v[6].f.y, v[7].f.y);
    __syncthreads();

    // ---- compute: acc[r][b] = sum over k-slice (k = kk*16+kq) of w[r][k]*h[k][b]
    float acc[4][8] = {};
    #pragma unroll 4
    for (int kk=0; kk<32; ++kk){
      int k = kk*16 + kq;
      float2 wA = *(const float2*)&Wt[k*66 + 4*rq];
      float2 wB = *(const float2*)&Wt[k*66 + 4*rq + 2];
      float4 ha = hta[k];
      float4 hb = htb[k];
      float hvv[8] = {ha.x,ha.y,ha.z,ha.w,hb.x,hb.y,hb.z,hb.w};
      #pragma unroll
      for (int i=0;i<8;++i){
        acc[0][i] = fmaf(wA.x, hvv[i], acc[0][i]);
        acc[1][i] = fmaf(wA.y, hvv[i], acc[1][i]);
        acc[2][i] = fmaf(wB.x, hvv[i], acc[2][i]);
        acc[3][i] = fmaf(wB.y, hvv[i], acc[3][i]);
      }
    }
    // ---- butterfly reduce over the 16-lane kq groups
    #pragma unroll
    for (int r=0;r<4;++r)
      #pragma unroll
      for (int i=0;i<8;++i){
        float s = acc[r][i];
        s += __shfl_xor(s, 1, 64);
        s += __shfl_xor(s, 2, 64);
        s += __shfl_xor(s, 4, 64);
        s += __shfl_xor(s, 8, 64);
        acc[r][i] = s;
      }
    // ---- epilogue: lane kq=b (b<8) stores h(j0),h(j0+1) for batch b as one u64 atomic
    if (kq < 8){
      int b = kq;
      float gg0 = acc[0][b] + pg.x, gg1 = acc[1][b] + pg.y;
      float oo0 = acc[2][b] + po.x, oo1 = acc[3][b] + po.y;
      F2U64 h2;
      h2.f.x = sigm_(oo0)*tanh_(tanh_(gg0));
      h2.f.y = sigm_(oo1)*tanh_(tanh_(gg1));
      __hip_atomic_store((unsigned long long*)
        (h_buf + (size_t)(1-par)*(B_*H_) + (size_t)(gb0 + b)*H_ + j0),
        h2.u, __ATOMIC_RELAXED, __HIP_MEMORY_SCOPE_AGENT);
    }
    __syncthreads();   // per-wave vmcnt(0): h loads consumed AND h stores visible
    if (t+1 < T_){
      if (tid == 0)
        __hip_atomic_store(bgflags + js, (unsigned)(t+1),
                           __ATOMIC_RELAXED, __HIP_MEMORY_SCOPE_AGENT);
      if (kq < 8){   // prefetch next step's P; overlaps peers' completion
        size_t prow = ((size_t)(t+1)*B_ + gb0 + kq)*1024;
        pg = *(const float2*)&P[prow + j0];
        po = *(const float2*)&P[prow + 512 + j0];
      }
    }
  }
}

// ---------------- classifier: out = hT @ w_out.T + b_out ----------------
__global__ __launch_bounds__(256) void k_cls(
  const float* __restrict__ hT, const float* __restrict__ w_out,
  const float* __restrict__ b_out, float* __restrict__ out)
{
  __shared__ float wt[32*68];     // [k][l] k-major
  __shared__ float htl[32*132];   // [k][b]
  int l0 = blockIdx.x * 64;       // 625 blocks
  int tid = threadIdx.x;
  int lq = tid >> 4, bq = tid & 15;
  float acc[4][8] = {};
  for (int kc=0; kc<16; ++kc){
    int k0 = kc*32;
    __syncthreads();
    for (int it=0; it<8; ++it){
      int e = it*256 + tid; int k = e & 31, l = e >> 5;
      wt[k*68 + l] = w_out[(size_t)(l0+l)*H_ + k0 + k];
    }
    for (int it=0; it<16; ++it){
      int e = it*256 + tid; int k = e & 31, b = e >> 5;
      htl[k*132 + b] = hT[(size_t)b*H_ + k0 + k];
    }
    __syncthreads();
    #pragma unroll 4
    for (int k=0;k<32;++k){
      float4 w4 = *(const float4*)&wt[k*68 + lq*4];
      float4 h0 = *(const float4*)&htl[k*132 + bq*8];
      float4 h1 = *(const float4*)&htl[k*132 + bq*8 + 4];
      float wv[4] = {w4.x,w4.y,w4.z,w4.w};
      float hv[8] = {h0.x,h0.y,h0.z,h0.w,h1.x,h1.y,h1.z,h1.w};
      #pragma unroll
      for (int m=0;m<4;++m)
        #pragma unroll
        for (int i=0;i<8;++i) acc[m][i] = fmaf(wv[m], hv[i], acc[m][i]);
    }
  }
  int l = l0 + lq*4;
  float4 bo = *(const float4*)&b_out[l];
  #pragma unroll
  for (int i=0;i<8;++i){
    int b = bq*8 + i;
    float4 o4;
    o4.x = acc[0][i] + bo.x; o4.y = acc[1][i] + bo.y;
    o4.z = acc[2][i] + bo.z; o4.w = acc[3][i] + bo.w;
    *(float4*)&out[(size_t)b*L_ + l] = o4;
  }
}

extern "C" void kernel_launch(void* const* d_in, const int* in_sizes, int n_in,
                              void* d_out, int out_size, void* d_ws, size_t ws_size,
                              hipStream_t stream) {
  const int*   batch_l = (const int*)  d_in[0];
  const float* t_ld    = (const float*)d_in[1];
  const float* t_hd    = (const float*)d_in[2];
  const int*   t_l     = (const int*)  d_in[3];
  const int*   t_h     = (const int*)  d_in[4];
  const float* d_ld    = (const float*)d_in[5];
  const float* d_hd    = (const float*)d_in[6];
  const int*   d_l     = (const int*)  d_in[7];
  const int*   d_h     = (const int*)  d_in[8];
  const float* embed_l = (const float*)d_in[9];
  const float* embed_s = (const float*)d_in[10];
  const float* embed_q = (const float*)d_in[11];
  const float* w_ih    = (const float*)d_in[12];
  const float* w_hh    = (const float*)d_in[13];
  const float* w_s     = (const float*)d_in[14];
  const float* w_q     = (const float*)d_in[15];
  const float* b_ih    = (const float*)d_in[16];
  const float* b_hh    = (const float*)d_in[17];
  const float* w_out   = (const float*)d_in[18];
  const float* b_out   = (const float*)d_in[19];
  float* out = (float*)d_out;

  // workspace layout (float offsets)
  float* ws = (float*)d_ws;
  const size_t P_off   = 0;                         // 13107200 f
  const size_t h_off   = 13107200;                  // 131072 f (2*B*H double buffer)
  const size_t es_off  = h_off + 131072;            // 5120 f
  const size_t eq_off  = es_off + 5120;             // 5120 f
  const size_t flg_off = eq_off + 5120;             // 256 u32 (16 bg x 16 js, 64B/bg)
  const size_t need_bytes = (flg_off + 256)*4 + 64;
  if (ws_size < need_bytes) return;

  float* P        = ws + P_off;
  float* h_buf    = ws + h_off;
  float* es_proj  = ws + es_off;
  float* eq_proj  = ws + eq_off;
  unsigned* flags = (unsigned*)(ws + flg_off);

  hipFuncSetAttribute(reinterpret_cast<const void*>(k_rec),
                      hipFuncAttributeMaxDynamicSharedMemorySize, 151552);

  k_zero<<<513, 256, 0, stream>>>(h_buf, flags);
  k_prep<<<40, 256, 0, stream>>>(embed_s, embed_q, w_s, w_q, es_proj, eq_proj);
  k_phase1<<<dim3(200,16), 256, 0, stream>>>(batch_l, embed_l, w_ih, b_ih, b_hh,
      t_ld, t_hd, t_l, t_h, d_ld, d_hd, d_l, d_h, es_proj, eq_proj, P);
  k_rec<<<256, 256, 151552, stream>>>(w_hh, P, h_buf, flags);
  k_cls<<<625, 256, 0, stream>>>(h_buf, w_out, b_out, out);
}